// Round 1
// baseline (377.612 us; speedup 1.0000x reference)
//
#include <hip/hip_runtime.h>

// GCN forward: two GCNConv layers + linear head.
// N=50000 nodes, E=800000 edges, feats 64 -> 128 -> 32 -> 32.
// Factorization: out = dinv[d] * sum_{s in N(d)+self} (dinv[s]*h[s]) applied per layer.
// Layer1 aggregates BEFORE GEMM (64 feats), layer2 AFTER GEMM (32 feats).

static constexpr int N  = 50000;
static constexpr int E  = 800000;
static constexpr int F0 = 64;    // input feats
static constexpr int F1 = 128;   // hidden
static constexpr int F2 = 32;    // classes

// ---- degree / dinv ----
__global__ void k_deg_init(float* __restrict__ deg) {
  int n = blockIdx.x * 256 + threadIdx.x;
  if (n < N) deg[n] = 1.0f;                      // self-loop
}
__global__ void k_deg_edges(const int* __restrict__ dst, float* __restrict__ deg) {
  int e = blockIdx.x * 256 + threadIdx.x;
  if (e < E) atomicAdd(&deg[dst[e]], 1.0f);
}
__global__ void k_dinv(float* __restrict__ deg) {
  int n = blockIdx.x * 256 + threadIdx.x;
  if (n < N) deg[n] = rsqrtf(deg[n]);            // deg >= 1 always
}

// ---- layer 1: aggregate x*dinv (64 feats). AX init = self-loop term. ----
__global__ void k_ax_init(const float* __restrict__ x, const float* __restrict__ dinv,
                          float* __restrict__ AX) {
  int i = blockIdx.x * 256 + threadIdx.x;        // one float4 per thread
  if (i < N * (F0 / 4)) {
    int n = i / (F0 / 4);
    float4 v = reinterpret_cast<const float4*>(x)[i];
    float d = dinv[n];
    v.x *= d; v.y *= d; v.z *= d; v.w *= d;
    reinterpret_cast<float4*>(AX)[i] = v;
  }
}

__global__ void k_scatter1(const int* __restrict__ src, const int* __restrict__ dst,
                           const float* __restrict__ x, const float* __restrict__ dinv,
                           float* __restrict__ AX) {
  int i = blockIdx.x * 256 + threadIdx.x;        // (edge, feat): one wave = one edge
  if (i >= E * F0) return;
  int e = i >> 6, f = i & (F0 - 1);
  int s = src[e], d = dst[e];
  float v = x[s * F0 + f] * dinv[s];
  atomicAdd(&AX[d * F0 + f], v);
}

// ---- GEMM1: H1r = relu(dinv[n] * AX[n,:] @ W1 + b1)  [N,64]@[64,128] ----
__global__ __launch_bounds__(256) void k_gemm1(const float* __restrict__ AX,
    const float* __restrict__ dinv, const float* __restrict__ W1,
    const float* __restrict__ b1, float* __restrict__ H1r) {
  __shared__ float Ws[F0][F1];   // 32 KB
  __shared__ float Xs[32][F0];   // 8 KB
  const int tid = threadIdx.x;
  const int row0 = blockIdx.x * 32;
  for (int i = tid; i < F0 * F1 / 4; i += 256)
    reinterpret_cast<float4*>(&Ws[0][0])[i] = reinterpret_cast<const float4*>(W1)[i];
  for (int i = tid; i < 32 * (F0 / 4); i += 256) {
    int r = i / (F0 / 4);
    int n = row0 + r;
    float4 v = make_float4(0.f, 0.f, 0.f, 0.f);
    if (n < N) {
      v = reinterpret_cast<const float4*>(AX)[n * (F0 / 4) + (i - r * (F0 / 4))];
      float d = dinv[n];
      v.x *= d; v.y *= d; v.z *= d; v.w *= d;
    }
    reinterpret_cast<float4*>(&Xs[0][0])[i] = v;
  }
  __syncthreads();
  const int col = tid & (F1 - 1);
  const int rg  = tid >> 7;                      // 0..1
  float acc[16];
  #pragma unroll
  for (int r = 0; r < 16; ++r) acc[r] = 0.f;
  for (int k = 0; k < F0; ++k) {
    float w = Ws[k][col];
    #pragma unroll
    for (int r = 0; r < 16; ++r) acc[r] += Xs[rg + 2 * r][k] * w;
  }
  const float bb = b1[col];
  #pragma unroll
  for (int r = 0; r < 16; ++r) {
    int n = row0 + rg + 2 * r;
    if (n < N) H1r[n * F1 + col] = fmaxf(acc[r] + bb, 0.f);
  }
}

// ---- GEMM2: H2s = (H1r @ W2) * dinv[n]; also init A2 (=d_out chunk1) with self-loop ----
__global__ __launch_bounds__(256) void k_gemm2(const float* __restrict__ H1r,
    const float* __restrict__ dinv, const float* __restrict__ W2,
    float* __restrict__ H2s, float* __restrict__ A2) {
  __shared__ float Ws[F1][F2];   // 16 KB
  __shared__ float Xs[32][F1];   // 16 KB
  const int tid = threadIdx.x;
  const int row0 = blockIdx.x * 32;
  for (int i = tid; i < F1 * F2 / 4; i += 256)
    reinterpret_cast<float4*>(&Ws[0][0])[i] = reinterpret_cast<const float4*>(W2)[i];
  for (int i = tid; i < 32 * (F1 / 4); i += 256) {
    int r = i / (F1 / 4);
    int n = row0 + r;
    float4 v = make_float4(0.f, 0.f, 0.f, 0.f);
    if (n < N)
      v = reinterpret_cast<const float4*>(H1r)[n * (F1 / 4) + (i - r * (F1 / 4))];
    reinterpret_cast<float4*>(&Xs[0][0])[i] = v;
  }
  __syncthreads();
  const int col = tid & (F2 - 1);
  const int rg  = tid >> 5;                      // 0..7
  float acc[4] = {0.f, 0.f, 0.f, 0.f};
  for (int k = 0; k < F1; ++k) {
    float w = Ws[k][col];
    #pragma unroll
    for (int r = 0; r < 4; ++r) acc[r] += Xs[rg + 8 * r][k] * w;
  }
  #pragma unroll
  for (int r = 0; r < 4; ++r) {
    int n = row0 + rg + 8 * r;
    if (n < N) {
      float v = acc[r] * dinv[n];
      H2s[n * F2 + col] = v;
      A2[n * F2 + col]  = v;                     // self-loop init, overwrites poison
    }
  }
}

__global__ void k_scatter2(const int* __restrict__ src, const int* __restrict__ dst,
                           const float* __restrict__ H2s, float* __restrict__ A2) {
  int i = blockIdx.x * 256 + threadIdx.x;        // (edge, feat): 2 edges per wave
  if (i >= E * F2) return;
  int e = i >> 5, f = i & (F2 - 1);
  atomicAdd(&A2[dst[e] * F2 + f], H2s[src[e] * F2 + f]);
}

// ---- final: h2 = dinv*A2 + b2 (in place into d_out chunk1); out = h2 @ Wc + bc ----
__global__ __launch_bounds__(256) void k_final(const float* __restrict__ dinv,
    const float* __restrict__ b2, const float* __restrict__ Wc,
    const float* __restrict__ bc, float* __restrict__ out, float* __restrict__ h2) {
  __shared__ float Wcs[F2][F2];  // 4 KB
  __shared__ float Hs[8][F2];
  const int tid = threadIdx.x;
  for (int i = tid; i < F2 * F2; i += 256) Wcs[i / F2][i % F2] = Wc[i];
  const int r = tid >> 5, j = tid & 31;
  const int n = blockIdx.x * 8 + r;
  float h = 0.f;
  if (n < N) h = dinv[n] * h2[n * F2 + j] + b2[j];
  Hs[r][j] = h;
  __syncthreads();
  if (n < N) {
    h2[n * F2 + j] = h;                          // final h2 output (in place)
    float acc = bc[j];
    #pragma unroll
    for (int k = 0; k < F2; ++k) acc += Hs[r][k] * Wcs[k][j];
    out[n * F2 + j] = acc;
  }
}

extern "C" void kernel_launch(void* const* d_in, const int* in_sizes, int n_in,
                              void* d_out, int out_size, void* d_ws, size_t ws_size,
                              hipStream_t stream) {
  const float* x  = (const float*)d_in[0];
  const int*   ei = (const int*)d_in[1];
  const int*   src = ei;                 // edge_index[0]
  const int*   dst = ei + E;             // edge_index[1]
  const float* W1 = (const float*)d_in[2];
  const float* b1 = (const float*)d_in[3];
  const float* W2 = (const float*)d_in[4];
  const float* b2 = (const float*)d_in[5];
  const float* Wc = (const float*)d_in[6];
  const float* bc = (const float*)d_in[7];

  float* out = (float*)d_out;                    // [N, 32] logits
  float* h2  = out + (size_t)N * F2;             // [N, 32] hidden out; doubles as A2 accum

  float* deg = (float*)d_ws;                     // N floats (becomes dinv in place)
  float* AX  = deg + 50048;                      // N*64
  float* H1r = AX + (size_t)N * F0;              // N*128
  float* H2s = H1r + (size_t)N * F1;             // N*32
  // total ws use: ~45 MB

  k_deg_init<<<(N + 255) / 256, 256, 0, stream>>>(deg);
  k_deg_edges<<<(E + 255) / 256, 256, 0, stream>>>(dst, deg);
  k_dinv<<<(N + 255) / 256, 256, 0, stream>>>(deg);
  k_ax_init<<<(N * (F0 / 4) + 255) / 256, 256, 0, stream>>>(x, deg, AX);
  k_scatter1<<<(E * F0 + 255) / 256, 256, 0, stream>>>(src, dst, x, deg, AX);
  k_gemm1<<<(N + 31) / 32, 256, 0, stream>>>(AX, deg, W1, b1, H1r);
  k_gemm2<<<(N + 31) / 32, 256, 0, stream>>>(H1r, deg, W2, H2s, h2);
  k_scatter2<<<(E * F2 + 255) / 256, 256, 0, stream>>>(src, dst, H2s, h2);
  k_final<<<(N + 7) / 8, 256, 0, stream>>>(deg, b2, Wc, bc, out, h2);
}

// Round 2
// 252.608 us; speedup vs baseline: 1.4948x; 1.4948x over previous
//
#include <hip/hip_runtime.h>

// GCN forward: two GCNConv layers + linear head.
// Round 2: CSR gather aggregation (no feature-space atomics).
// out = dinv[d] * sum_{s in N(d)+self} (dinv[s]*h[s]) per layer.
// Layer1 aggregates BEFORE GEMM (64 feats), layer2 AFTER its GEMM (32 feats).

static constexpr int N  = 50000;
static constexpr int E  = 800000;
static constexpr int F0 = 64;    // input feats
static constexpr int F1 = 128;   // hidden
static constexpr int F2 = 32;    // classes

// ---- CSR build ----
__global__ void k_init(int* __restrict__ cnt) {
  int n = blockIdx.x * 256 + threadIdx.x;
  if (n < N) cnt[n] = 0;
}
__global__ void k_count(const int* __restrict__ dst, int* __restrict__ cnt) {
  int e = blockIdx.x * 256 + threadIdx.x;
  if (e < E) atomicAdd(&cnt[dst[e]], 1);
}
// per-block exclusive scan; cursor[i] = excl-scan within block, bsum[b] = block total
__global__ __launch_bounds__(256) void k_scan1(const int* __restrict__ cnt,
                                               int* __restrict__ cursor,
                                               int* __restrict__ bsum) {
  __shared__ int s[256];
  int tid = threadIdx.x;
  int i = blockIdx.x * 256 + tid;
  int v = (i < N) ? cnt[i] : 0;
  s[tid] = v; __syncthreads();
  for (int off = 1; off < 256; off <<= 1) {
    int t = (tid >= off) ? s[tid - off] : 0;
    __syncthreads();
    s[tid] += t;
    __syncthreads();
  }
  if (i < N) cursor[i] = s[tid] - v;
  if (tid == 255) bsum[blockIdx.x] = s[255];
}
__global__ __launch_bounds__(256) void k_scan2(int* __restrict__ bsum, int nb) {
  __shared__ int s[256];
  int tid = threadIdx.x;
  int v = (tid < nb) ? bsum[tid] : 0;
  s[tid] = v; __syncthreads();
  for (int off = 1; off < 256; off <<= 1) {
    int t = (tid >= off) ? s[tid - off] : 0;
    __syncthreads();
    s[tid] += t;
    __syncthreads();
  }
  bsum[tid] = s[tid] - v;   // exclusive block offsets
}
__global__ void k_scan3(int* __restrict__ cursor, const int* __restrict__ bsum) {
  int i = blockIdx.x * 256 + threadIdx.x;
  if (i < N) cursor[i] += bsum[blockIdx.x];
}
__global__ void k_dinv(const int* __restrict__ cnt, float* __restrict__ dinv) {
  int n = blockIdx.x * 256 + threadIdx.x;
  if (n < N) dinv[n] = rsqrtf((float)(cnt[n] + 1));   // +1 self-loop
}
__global__ void k_fill(const int* __restrict__ src, const int* __restrict__ dst,
                       int* __restrict__ cursor, int* __restrict__ ssrc) {
  int e = blockIdx.x * 256 + threadIdx.x;
  if (e < E) {
    int pos = atomicAdd(&cursor[dst[e]], 1);
    ssrc[pos] = src[e];
  }
}
// after k_fill: cursor[n] = row end; row start = cursor[n] - cnt[n]

// ---- layer-1 aggregation: AX[n] = dinv[n] * (x[n]*dinv[n] + sum_s x[s]*dinv[s]) ----
__global__ __launch_bounds__(256) void k_agg1(const int* __restrict__ cursor,
    const int* __restrict__ cnt, const int* __restrict__ ssrc,
    const float* __restrict__ x, const float* __restrict__ dinv,
    float* __restrict__ AX) {
  int gw = (blockIdx.x * 256 + threadIdx.x) >> 6;   // node (one wave each)
  int lane = threadIdx.x & 63;                      // feature
  if (gw >= N) return;
  int end = cursor[gw], deg = cnt[gw], start = end - deg;
  float acc = x[gw * F0 + lane] * dinv[gw];         // self loop
  for (int e0 = start; e0 < end; e0 += 64) {
    int m = end - e0; if (m > 64) m = 64;
    int idx = e0 + lane; if (idx > end - 1) idx = end - 1;
    int sl = ssrc[idx];
    float dl = dinv[sl];
    for (int j = 0; j < m; ++j) {
      int s = __shfl(sl, j);
      float dv = __shfl(dl, j);
      acc += x[s * F0 + lane] * dv;
    }
  }
  AX[gw * F0 + lane] = acc * dinv[gw];
}

// ---- GEMM1: H1r = relu(AX @ W1 + b1)  [N,64]@[64,128] ----
__global__ __launch_bounds__(256) void k_gemm1(const float* __restrict__ AX,
    const float* __restrict__ W1, const float* __restrict__ b1,
    float* __restrict__ H1r) {
  __shared__ float Ws[F0][F1];   // 32 KB
  __shared__ float Xs[32][F0];   // 8 KB
  const int tid = threadIdx.x;
  const int row0 = blockIdx.x * 32;
  for (int i = tid; i < F0 * F1 / 4; i += 256)
    reinterpret_cast<float4*>(&Ws[0][0])[i] = reinterpret_cast<const float4*>(W1)[i];
  for (int i = tid; i < 32 * (F0 / 4); i += 256) {
    int r = i / (F0 / 4);
    int n = row0 + r;
    float4 v = make_float4(0.f, 0.f, 0.f, 0.f);
    if (n < N)
      v = reinterpret_cast<const float4*>(AX)[n * (F0 / 4) + (i - r * (F0 / 4))];
    reinterpret_cast<float4*>(&Xs[0][0])[i] = v;
  }
  __syncthreads();
  const int col = tid & (F1 - 1);
  const int rg  = tid >> 7;                      // 0..1
  float acc[16];
  #pragma unroll
  for (int r = 0; r < 16; ++r) acc[r] = 0.f;
  for (int k = 0; k < F0; ++k) {
    float w = Ws[k][col];
    #pragma unroll
    for (int r = 0; r < 16; ++r) acc[r] += Xs[rg + 2 * r][k] * w;
  }
  const float bb = b1[col];
  #pragma unroll
  for (int r = 0; r < 16; ++r) {
    int n = row0 + rg + 2 * r;
    if (n < N) H1r[n * F1 + col] = fmaxf(acc[r] + bb, 0.f);
  }
}

// ---- GEMM2: H2s = (H1r @ W2) * dinv[n]   (src-side prescale for layer-2 agg) ----
__global__ __launch_bounds__(256) void k_gemm2(const float* __restrict__ H1r,
    const float* __restrict__ dinv, const float* __restrict__ W2,
    float* __restrict__ H2s) {
  __shared__ float Ws[F1][F2];   // 16 KB
  __shared__ float Xs[32][F1];   // 16 KB
  const int tid = threadIdx.x;
  const int row0 = blockIdx.x * 32;
  for (int i = tid; i < F1 * F2 / 4; i += 256)
    reinterpret_cast<float4*>(&Ws[0][0])[i] = reinterpret_cast<const float4*>(W2)[i];
  for (int i = tid; i < 32 * (F1 / 4); i += 256) {
    int r = i / (F1 / 4);
    int n = row0 + r;
    float4 v = make_float4(0.f, 0.f, 0.f, 0.f);
    if (n < N)
      v = reinterpret_cast<const float4*>(H1r)[n * (F1 / 4) + (i - r * (F1 / 4))];
    reinterpret_cast<float4*>(&Xs[0][0])[i] = v;
  }
  __syncthreads();
  const int col = tid & (F2 - 1);
  const int rg  = tid >> 5;                      // 0..7
  float acc[4] = {0.f, 0.f, 0.f, 0.f};
  for (int k = 0; k < F1; ++k) {
    float w = Ws[k][col];
    #pragma unroll
    for (int r = 0; r < 4; ++r) acc[r] += Xs[rg + 8 * r][k] * w;
  }
  #pragma unroll
  for (int r = 0; r < 4; ++r) {
    int n = row0 + rg + 8 * r;
    if (n < N) H2s[n * F2 + col] = acc[r] * dinv[n];
  }
}

// ---- layer-2 aggregation + bias: h2[n] = dinv[n]*(H2s[n] + sum_s H2s[s]) + b2 ----
__global__ __launch_bounds__(256) void k_agg2(const int* __restrict__ cursor,
    const int* __restrict__ cnt, const int* __restrict__ ssrc,
    const float* __restrict__ H2s, const float* __restrict__ dinv,
    const float* __restrict__ b2, float* __restrict__ h2) {
  int gw = (blockIdx.x * 256 + threadIdx.x) >> 6;   // node (one wave each)
  int lane = threadIdx.x & 63;
  int f = lane & 31, half = lane >> 5;
  if (gw >= N) return;
  int end = cursor[gw], deg = cnt[gw], start = end - deg;
  float acc = (half == 0) ? H2s[gw * F2 + f] : 0.f; // self loop
  for (int e0 = start; e0 < end; e0 += 64) {
    int m = end - e0; if (m > 64) m = 64;
    int idx = e0 + lane; if (idx > end - 1) idx = end - 1;
    int sl = ssrc[idx];
    for (int j = 0; j < m; j += 2) {
      int jj = j + half;                            // halves take alternating edges
      int s = __shfl(sl, jj);                      // jj<=63 always; sl clamped-valid
      float v = H2s[s * F2 + f];
      if (jj < m) acc += v;
    }
  }
  acc += __shfl_xor(acc, 32);
  if (half == 0) h2[gw * F2 + f] = dinv[gw] * acc + b2[f];
}

// ---- head: out = h2 @ Wc + bc ----
__global__ __launch_bounds__(256) void k_head(const float* __restrict__ h2,
    const float* __restrict__ Wc, const float* __restrict__ bc,
    float* __restrict__ out) {
  __shared__ float Wcs[F2][F2];  // 4 KB
  __shared__ float Hs[8][F2];
  const int tid = threadIdx.x;
  for (int i = tid; i < F2 * F2; i += 256) Wcs[i >> 5][i & 31] = Wc[i];
  const int r = tid >> 5, j = tid & 31;
  const int n = blockIdx.x * 8 + r;
  float h = (n < N) ? h2[n * F2 + j] : 0.f;
  Hs[r][j] = h;
  __syncthreads();
  if (n < N) {
    float acc = bc[j];
    #pragma unroll
    for (int k = 0; k < F2; ++k) acc += Hs[r][k] * Wcs[k][j];
    out[n * F2 + j] = acc;
  }
}

extern "C" void kernel_launch(void* const* d_in, const int* in_sizes, int n_in,
                              void* d_out, int out_size, void* d_ws, size_t ws_size,
                              hipStream_t stream) {
  const float* x  = (const float*)d_in[0];
  const int*   ei = (const int*)d_in[1];
  const int*   src = ei;                 // edge_index[0]
  const int*   dst = ei + E;             // edge_index[1]
  const float* W1 = (const float*)d_in[2];
  const float* b1 = (const float*)d_in[3];
  const float* W2 = (const float*)d_in[4];
  const float* b2 = (const float*)d_in[5];
  const float* Wc = (const float*)d_in[6];
  const float* bc = (const float*)d_in[7];

  float* out = (float*)d_out;                    // [N, 32] logits
  float* h2  = out + (size_t)N * F2;             // [N, 32] hidden output

  // workspace layout (~42 MB)
  int*   cnt    = (int*)d_ws;                    // N
  int*   cursor = cnt + N;                       // N
  int*   bsum   = cursor + N;                    // 256
  float* dinv   = (float*)(bsum + 256);          // N
  int*   ssrc   = (int*)(dinv + N);              // E
  float* AX     = (float*)(ssrc + E);            // N*64
  float* H1r    = AX + (size_t)N * F0;           // N*128
  float* H2s    = AX;                            // N*32, aliases AX (dead after gemm1)

  const int nbN = (N + 255) / 256;               // 196
  const int nbE = (E + 255) / 256;               // 3125

  k_init <<<nbN, 256, 0, stream>>>(cnt);
  k_count<<<nbE, 256, 0, stream>>>(dst, cnt);
  k_scan1<<<nbN, 256, 0, stream>>>(cnt, cursor, bsum);
  k_scan2<<<1,   256, 0, stream>>>(bsum, nbN);
  k_scan3<<<nbN, 256, 0, stream>>>(cursor, bsum);
  k_dinv <<<nbN, 256, 0, stream>>>(cnt, dinv);
  k_fill <<<nbE, 256, 0, stream>>>(src, dst, cursor, ssrc);

  k_agg1 <<<(N + 3) / 4, 256, 0, stream>>>(cursor, cnt, ssrc, x, dinv, AX);
  k_gemm1<<<(N + 31) / 32, 256, 0, stream>>>(AX, W1, b1, H1r);
  k_gemm2<<<(N + 31) / 32, 256, 0, stream>>>(H1r, dinv, W2, H2s);
  k_agg2 <<<(N + 3) / 4, 256, 0, stream>>>(cursor, cnt, ssrc, H2s, dinv, b2, h2);
  k_head <<<(N + 7) / 8, 256, 0, stream>>>(h2, Wc, bc, out);
}

// Round 3
// 228.576 us; speedup vs baseline: 1.6520x; 1.1051x over previous
//
#include <hip/hip_runtime.h>

// GCN forward: two GCNConv layers + linear head.
// Round 3: CSR gather + prescaled sources + scalar edge-stream + unroll-8 MLP.
// out = dinv[d] * sum_{s in N(d)+self} (dinv[s]*h[s]) per layer.
// Layer1 aggregates BEFORE GEMM (64 feats), layer2 AFTER its GEMM (32 feats).

static constexpr int N  = 50000;
static constexpr int E  = 800000;
static constexpr int F0 = 64;    // input feats
static constexpr int F1 = 128;   // hidden
static constexpr int F2 = 32;    // classes

// ---- CSR build ----
__global__ void k_init(int* __restrict__ cnt) {
  int n = blockIdx.x * 256 + threadIdx.x;
  if (n < N) cnt[n] = 0;
}
__global__ void k_count(const int* __restrict__ dst, int* __restrict__ cnt) {
  int e = blockIdx.x * 256 + threadIdx.x;
  if (e < E) atomicAdd(&cnt[dst[e]], 1);
}
__global__ __launch_bounds__(256) void k_scan1(const int* __restrict__ cnt,
                                               int* __restrict__ cursor,
                                               int* __restrict__ bsum) {
  __shared__ int s[256];
  int tid = threadIdx.x;
  int i = blockIdx.x * 256 + tid;
  int v = (i < N) ? cnt[i] : 0;
  s[tid] = v; __syncthreads();
  for (int off = 1; off < 256; off <<= 1) {
    int t = (tid >= off) ? s[tid - off] : 0;
    __syncthreads();
    s[tid] += t;
    __syncthreads();
  }
  if (i < N) cursor[i] = s[tid] - v;
  if (tid == 255) bsum[blockIdx.x] = s[255];
}
__global__ __launch_bounds__(256) void k_scan2(int* __restrict__ bsum, int nb) {
  __shared__ int s[256];
  int tid = threadIdx.x;
  int v = (tid < nb) ? bsum[tid] : 0;
  s[tid] = v; __syncthreads();
  for (int off = 1; off < 256; off <<= 1) {
    int t = (tid >= off) ? s[tid - off] : 0;
    __syncthreads();
    s[tid] += t;
    __syncthreads();
  }
  bsum[tid] = s[tid] - v;
}
__global__ void k_scan3(int* __restrict__ cursor, const int* __restrict__ bsum) {
  int i = blockIdx.x * 256 + threadIdx.x;
  if (i < N) cursor[i] += bsum[blockIdx.x];
}
__global__ void k_dinv(const int* __restrict__ cnt, float* __restrict__ dinv) {
  int n = blockIdx.x * 256 + threadIdx.x;
  if (n < N) dinv[n] = rsqrtf((float)(cnt[n] + 1));   // +1 self-loop
}
__global__ void k_fill(const int* __restrict__ src, const int* __restrict__ dst,
                       int* __restrict__ cursor, int* __restrict__ ssrc) {
  int e = blockIdx.x * 256 + threadIdx.x;
  if (e < E) {
    int pos = atomicAdd(&cursor[dst[e]], 1);
    ssrc[pos] = src[e];
  }
}
// after k_fill: cursor[n] = row end; row start = cursor[n] - cnt[n]

// ---- xs = x * dinv[n]  (source prescale, removes per-edge dinv gather) ----
__global__ void k_prescale(const float* __restrict__ x, const float* __restrict__ dinv,
                           float* __restrict__ xs) {
  int i = blockIdx.x * 256 + threadIdx.x;        // one float4 per thread
  if (i < N * (F0 / 4)) {
    int n = i / (F0 / 4);
    float4 v = reinterpret_cast<const float4*>(x)[i];
    float d = dinv[n];
    v.x *= d; v.y *= d; v.z *= d; v.w *= d;
    reinterpret_cast<float4*>(xs)[i] = v;
  }
}

// ---- layer-1 aggregation: AX[n] = dinv[n] * (xs[n] + sum_s xs[s]) ----
__global__ __launch_bounds__(256) void k_agg1(const int* __restrict__ rowend,
    const int* __restrict__ cnt, const int* __restrict__ ssrc,
    const float* __restrict__ xs, const float* __restrict__ dinv,
    float* __restrict__ AX) {
  int gw = (blockIdx.x * 256 + threadIdx.x) >> 6;   // node (one wave each)
  int lane = threadIdx.x & 63;                      // feature
  if (gw >= N) return;
  int end   = __builtin_amdgcn_readfirstlane(rowend[gw]);
  int deg   = __builtin_amdgcn_readfirstlane(cnt[gw]);
  int start = end - deg;
  float a0 = xs[(size_t)gw * F0 + lane];            // self loop (already *dinv)
  float a1 = 0.f, a2 = 0.f, a3 = 0.f;
  for (int e0 = start; e0 < end; e0 += 8) {
    #pragma unroll
    for (int u = 0; u < 8; ++u) {
      int j  = e0 + u;
      int jc = (j < end) ? j : start;               // uniform clamp
      int s  = ssrc[jc];                            // wave-uniform -> s_load
      float v = xs[(size_t)s * F0 + lane];
      v = (j < end) ? v : 0.f;                      // uniform mask
      if ((u & 3) == 0) a0 += v;
      else if ((u & 3) == 1) a1 += v;
      else if ((u & 3) == 2) a2 += v;
      else a3 += v;
    }
  }
  AX[(size_t)gw * F0 + lane] = ((a0 + a2) + (a1 + a3)) * dinv[gw];
}

// ---- GEMM1: H1r = relu(AX @ W1 + b1)  [N,64]@[64,128] ----
__global__ __launch_bounds__(256) void k_gemm1(const float* __restrict__ AX,
    const float* __restrict__ W1, const float* __restrict__ b1,
    float* __restrict__ H1r) {
  __shared__ float Ws[F0][F1];   // 32 KB
  __shared__ float Xs[32][F0];   // 8 KB
  const int tid = threadIdx.x;
  const int row0 = blockIdx.x * 32;
  for (int i = tid; i < F0 * F1 / 4; i += 256)
    reinterpret_cast<float4*>(&Ws[0][0])[i] = reinterpret_cast<const float4*>(W1)[i];
  for (int i = tid; i < 32 * (F0 / 4); i += 256) {
    int r = i / (F0 / 4);
    int n = row0 + r;
    float4 v = make_float4(0.f, 0.f, 0.f, 0.f);
    if (n < N)
      v = reinterpret_cast<const float4*>(AX)[n * (F0 / 4) + (i - r * (F0 / 4))];
    reinterpret_cast<float4*>(&Xs[0][0])[i] = v;
  }
  __syncthreads();
  const int col = tid & (F1 - 1);
  const int rg  = tid >> 7;                      // 0..1
  float acc[16];
  #pragma unroll
  for (int r = 0; r < 16; ++r) acc[r] = 0.f;
  for (int k = 0; k < F0; ++k) {
    float w = Ws[k][col];
    #pragma unroll
    for (int r = 0; r < 16; ++r) acc[r] += Xs[rg + 2 * r][k] * w;
  }
  const float bb = b1[col];
  #pragma unroll
  for (int r = 0; r < 16; ++r) {
    int n = row0 + rg + 2 * r;
    if (n < N) H1r[n * F1 + col] = fmaxf(acc[r] + bb, 0.f);
  }
}

// ---- GEMM2: H2s = (H1r @ W2) * dinv[n]   (src-side prescale for layer-2 agg) ----
__global__ __launch_bounds__(256) void k_gemm2(const float* __restrict__ H1r,
    const float* __restrict__ dinv, const float* __restrict__ W2,
    float* __restrict__ H2s) {
  __shared__ float Ws[F1][F2];   // 16 KB
  __shared__ float Xs[32][F1];   // 16 KB
  const int tid = threadIdx.x;
  const int row0 = blockIdx.x * 32;
  for (int i = tid; i < F1 * F2 / 4; i += 256)
    reinterpret_cast<float4*>(&Ws[0][0])[i] = reinterpret_cast<const float4*>(W2)[i];
  for (int i = tid; i < 32 * (F1 / 4); i += 256) {
    int r = i / (F1 / 4);
    int n = row0 + r;
    float4 v = make_float4(0.f, 0.f, 0.f, 0.f);
    if (n < N)
      v = reinterpret_cast<const float4*>(H1r)[n * (F1 / 4) + (i - r * (F1 / 4))];
    reinterpret_cast<float4*>(&Xs[0][0])[i] = v;
  }
  __syncthreads();
  const int col = tid & (F2 - 1);
  const int rg  = tid >> 5;                      // 0..7
  float acc[4] = {0.f, 0.f, 0.f, 0.f};
  for (int k = 0; k < F1; ++k) {
    float w = Ws[k][col];
    #pragma unroll
    for (int r = 0; r < 4; ++r) acc[r] += Xs[rg + 8 * r][k] * w;
  }
  #pragma unroll
  for (int r = 0; r < 4; ++r) {
    int n = row0 + rg + 8 * r;
    if (n < N) H2s[n * F2 + col] = acc[r] * dinv[n];
  }
}

// ---- layer-2 aggregation + bias: h2[n] = dinv[n]*(H2s[n] + sum_s H2s[s]) + b2 ----
__global__ __launch_bounds__(256) void k_agg2(const int* __restrict__ rowend,
    const int* __restrict__ cnt, const int* __restrict__ ssrc,
    const float* __restrict__ H2s, const float* __restrict__ dinv,
    const float* __restrict__ b2, float* __restrict__ h2) {
  int gw = (blockIdx.x * 256 + threadIdx.x) >> 6;   // node (one wave each)
  int lane = threadIdx.x & 63;
  int f = lane & 31, half = lane >> 5;
  if (gw >= N) return;
  int end   = __builtin_amdgcn_readfirstlane(rowend[gw]);
  int deg   = __builtin_amdgcn_readfirstlane(cnt[gw]);
  int start = end - deg;
  float a0 = (half == 0) ? H2s[(size_t)gw * F2 + f] : 0.f;  // self loop
  float a1 = 0.f, a2 = 0.f, a3 = 0.f;
  for (int e0 = start; e0 < end; e0 += 8) {
    #pragma unroll
    for (int u = 0; u < 4; ++u) {
      int ja = e0 + 2 * u, jb = ja + 1;
      int sa = ssrc[(ja < end) ? ja : start];       // uniform -> s_load
      int sb = ssrc[(jb < end) ? jb : start];
      int s  = half ? sb : sa;
      int j  = half ? jb : ja;
      float v = H2s[(size_t)s * F2 + f];
      v = (j < end) ? v : 0.f;
      if (u == 0) a0 += v;
      else if (u == 1) a1 += v;
      else if (u == 2) a2 += v;
      else a3 += v;
    }
  }
  float acc = (a0 + a2) + (a1 + a3);
  acc += __shfl_xor(acc, 32);
  if (half == 0) h2[(size_t)gw * F2 + f] = dinv[gw] * acc + b2[f];
}

// ---- head: out = h2 @ Wc + bc ----
__global__ __launch_bounds__(256) void k_head(const float* __restrict__ h2,
    const float* __restrict__ Wc, const float* __restrict__ bc,
    float* __restrict__ out) {
  __shared__ float Wcs[F2][F2];  // 4 KB
  __shared__ float Hs[8][F2];
  const int tid = threadIdx.x;
  for (int i = tid; i < F2 * F2; i += 256) Wcs[i >> 5][i & 31] = Wc[i];
  const int r = tid >> 5, j = tid & 31;
  const int n = blockIdx.x * 8 + r;
  float h = (n < N) ? h2[n * F2 + j] : 0.f;
  Hs[r][j] = h;
  __syncthreads();
  if (n < N) {
    float acc = bc[j];
    #pragma unroll
    for (int k = 0; k < F2; ++k) acc += Hs[r][k] * Wcs[k][j];
    out[n * F2 + j] = acc;
  }
}

extern "C" void kernel_launch(void* const* d_in, const int* in_sizes, int n_in,
                              void* d_out, int out_size, void* d_ws, size_t ws_size,
                              hipStream_t stream) {
  const float* x  = (const float*)d_in[0];
  const int*   ei = (const int*)d_in[1];
  const int*   src = ei;                 // edge_index[0]
  const int*   dst = ei + E;             // edge_index[1]
  const float* W1 = (const float*)d_in[2];
  const float* b1 = (const float*)d_in[3];
  const float* W2 = (const float*)d_in[4];
  const float* b2 = (const float*)d_in[5];
  const float* Wc = (const float*)d_in[6];
  const float* bc = (const float*)d_in[7];

  float* out = (float*)d_out;                    // [N, 32] logits
  float* h2  = out + (size_t)N * F2;             // [N, 32] hidden output

  // workspace layout (~42 MB)
  int*   cnt    = (int*)d_ws;                    // N
  int*   cursor = cnt + N;                       // N
  int*   bsum   = cursor + N;                    // 256
  float* dinv   = (float*)(bsum + 256);          // N
  int*   ssrc   = (int*)(dinv + N);              // E
  float* AX     = (float*)(ssrc + E);            // N*64
  float* big    = AX + (size_t)N * F0;           // N*128 region
  float* xs     = big;                           // N*64, dead after k_agg1
  float* H1r    = big;                           // N*128, written after xs dead
  float* H2s    = AX;                            // N*32, aliases AX (dead after gemm1)

  const int nbN = (N + 255) / 256;               // 196
  const int nbE = (E + 255) / 256;               // 3125

  k_init <<<nbN, 256, 0, stream>>>(cnt);
  k_count<<<nbE, 256, 0, stream>>>(dst, cnt);
  k_scan1<<<nbN, 256, 0, stream>>>(cnt, cursor, bsum);
  k_scan2<<<1,   256, 0, stream>>>(bsum, nbN);
  k_scan3<<<nbN, 256, 0, stream>>>(cursor, bsum);
  k_dinv <<<nbN, 256, 0, stream>>>(cnt, dinv);
  k_fill <<<nbE, 256, 0, stream>>>(src, dst, cursor, ssrc);

  k_prescale<<<(N * (F0 / 4) + 255) / 256, 256, 0, stream>>>(x, dinv, xs);
  k_agg1 <<<(N + 3) / 4, 256, 0, stream>>>(cursor, cnt, ssrc, xs, dinv, AX);
  k_gemm1<<<(N + 31) / 32, 256, 0, stream>>>(AX, W1, b1, H1r);
  k_gemm2<<<(N + 31) / 32, 256, 0, stream>>>(H1r, dinv, W2, H2s);
  k_agg2 <<<(N + 3) / 4, 256, 0, stream>>>(cursor, cnt, ssrc, H2s, dinv, b2, h2);
  k_head <<<(N + 7) / 8, 256, 0, stream>>>(h2, Wc, bc, out);
}

// Round 4
// 157.936 us; speedup vs baseline: 2.3909x; 1.4473x over previous
//
#include <hip/hip_runtime.h>

// GCN forward: two GCNConv layers + linear head.
// Round 4: CSR build via bucketed counting sort (zero global atomics, no
// cross-XCD line ping-pong). Aggregation = CSR gather with prescaled sources,
// scalar edge-stream, unroll-8 MLP. Layer1 aggregates BEFORE GEMM (64 feats),
// layer2 AFTER its GEMM (32 feats).

static constexpr int N  = 50000;
static constexpr int E  = 800000;
static constexpr int F0 = 64;    // input feats
static constexpr int F1 = 128;   // hidden
static constexpr int F2 = 32;    // classes

static constexpr int NBUK   = 196;   // ceil(N/256) buckets of 256 nodes (dst>>8)
static constexpr int CHUNK  = 4096;  // edges per histogram chunk
static constexpr int NCHUNK = 196;   // ceil(E/CHUNK)

// ---- B1: per-chunk LDS histogram over dst buckets ----
__global__ __launch_bounds__(256) void k_hist(const int* __restrict__ dst,
                                              int* __restrict__ hist) {
  __shared__ int hl[NBUK];
  int tid = threadIdx.x, c = blockIdx.x;
  for (int t = tid; t < NBUK; t += 256) hl[t] = 0;
  __syncthreads();
  int e0 = c * CHUNK, m = min(CHUNK, E - e0);
  for (int i = tid; i < m; i += 256)
    atomicAdd(&hl[dst[e0 + i] >> 8], 1);
  __syncthreads();
  for (int t = tid; t < NBUK; t += 256) hist[t * NCHUNK + c] = hl[t];
}

// ---- S1: per-bucket exclusive scan over chunks; bucket totals out ----
__global__ __launch_bounds__(256) void k_scanbk(int* __restrict__ hist,
                                                int* __restrict__ bucketBase) {
  __shared__ int s[256];
  int t = threadIdx.x, b = blockIdx.x;
  int v = (t < NCHUNK) ? hist[b * NCHUNK + t] : 0;
  s[t] = v; __syncthreads();
  for (int off = 1; off < 256; off <<= 1) {
    int u = (t >= off) ? s[t - off] : 0;
    __syncthreads(); s[t] += u; __syncthreads();
  }
  if (t < NCHUNK) hist[b * NCHUNK + t] = s[t] - v;
  if (t == 255) bucketBase[b] = s[255];
}

// ---- S2: exclusive scan of bucket totals (writes sentinel bucketBase[NBUK]=E) ----
__global__ __launch_bounds__(256) void k_scanbase(int* __restrict__ bucketBase) {
  __shared__ int s[256];
  int t = threadIdx.x;
  int v = (t < NBUK) ? bucketBase[t] : 0;
  s[t] = v; __syncthreads();
  for (int off = 1; off < 256; off <<= 1) {
    int u = (t >= off) ? s[t - off] : 0;
    __syncthreads(); s[t] += u; __syncthreads();
  }
  if (t <= NBUK) bucketBase[t] = s[t] - v;
}

// ---- B2: scatter edges into bucket-grouped order (packed (dlocal<<16)|src) ----
__global__ __launch_bounds__(256) void k_bucket(const int* __restrict__ src,
    const int* __restrict__ dst, const int* __restrict__ hist,
    const int* __restrict__ bucketBase, unsigned int* __restrict__ ebuf) {
  __shared__ int startL[NBUK];
  int tid = threadIdx.x, c = blockIdx.x;
  for (int t = tid; t < NBUK; t += 256)
    startL[t] = bucketBase[t] + hist[t * NCHUNK + c];
  __syncthreads();
  int e0 = c * CHUNK, m = min(CHUNK, E - e0);
  for (int i = tid; i < m; i += 256) {
    int e = e0 + i;
    int d = dst[e], s = src[e];
    int pos = atomicAdd(&startL[d >> 8], 1);           // LDS atomic
    ebuf[pos] = (unsigned int)s | ((unsigned int)(d & 255) << 16);
  }
}

// ---- B3: per-bucket CSR finalize: cnt/rowend/dinv + within-bucket sort ----
__global__ __launch_bounds__(256) void k_csr(const unsigned int* __restrict__ ebuf,
    const int* __restrict__ bucketBase, int* __restrict__ cnt,
    int* __restrict__ rowend, float* __restrict__ dinv, int* __restrict__ ssrc) {
  __shared__ int cl[256], sc[256], cur[256];
  int t = threadIdx.x, b = blockIdx.x;
  int base = bucketBase[b];
  int m = bucketBase[b + 1] - base;
  int node0 = b << 8;
  cl[t] = 0;
  __syncthreads();
  for (int i = t; i < m; i += 256)
    atomicAdd(&cl[(ebuf[base + i] >> 16) & 255], 1);
  __syncthreads();
  int v = cl[t];
  sc[t] = v; __syncthreads();
  for (int off = 1; off < 256; off <<= 1) {
    int u = (t >= off) ? sc[t - off] : 0;
    __syncthreads(); sc[t] += u; __syncthreads();
  }
  int excl = sc[t] - v;
  cur[t] = excl;
  int g = node0 + t;
  if (g < N) {
    cnt[g]    = v;
    rowend[g] = base + excl + v;
    dinv[g]   = rsqrtf((float)(v + 1));               // +1 self-loop
  }
  __syncthreads();
  for (int i = t; i < m; i += 256) {
    unsigned int p = ebuf[base + i];
    int d = (p >> 16) & 255;
    int r = atomicAdd(&cur[d], 1);                     // LDS atomic
    ssrc[base + r] = (int)(p & 0xFFFFu);
  }
}

// ---- xs = x * dinv[n]  (source prescale, removes per-edge dinv gather) ----
__global__ void k_prescale(const float* __restrict__ x, const float* __restrict__ dinv,
                           float* __restrict__ xs) {
  int i = blockIdx.x * 256 + threadIdx.x;        // one float4 per thread
  if (i < N * (F0 / 4)) {
    int n = i / (F0 / 4);
    float4 v = reinterpret_cast<const float4*>(x)[i];
    float d = dinv[n];
    v.x *= d; v.y *= d; v.z *= d; v.w *= d;
    reinterpret_cast<float4*>(xs)[i] = v;
  }
}

// ---- layer-1 aggregation: AX[n] = dinv[n] * (xs[n] + sum_s xs[s]) ----
__global__ __launch_bounds__(256) void k_agg1(const int* __restrict__ rowend,
    const int* __restrict__ cnt, const int* __restrict__ ssrc,
    const float* __restrict__ xs, const float* __restrict__ dinv,
    float* __restrict__ AX) {
  int gw = (blockIdx.x * 256 + threadIdx.x) >> 6;   // node (one wave each)
  int lane = threadIdx.x & 63;                      // feature
  if (gw >= N) return;
  int end   = __builtin_amdgcn_readfirstlane(rowend[gw]);
  int deg   = __builtin_amdgcn_readfirstlane(cnt[gw]);
  int start = end - deg;
  float a0 = xs[(size_t)gw * F0 + lane];            // self loop (already *dinv)
  float a1 = 0.f, a2 = 0.f, a3 = 0.f;
  for (int e0 = start; e0 < end; e0 += 8) {
    #pragma unroll
    for (int u = 0; u < 8; ++u) {
      int j  = e0 + u;
      int jc = (j < end) ? j : start;               // uniform clamp
      int s  = ssrc[jc];                            // wave-uniform -> s_load
      float v = xs[(size_t)s * F0 + lane];
      v = (j < end) ? v : 0.f;                      // uniform mask
      if ((u & 3) == 0) a0 += v;
      else if ((u & 3) == 1) a1 += v;
      else if ((u & 3) == 2) a2 += v;
      else a3 += v;
    }
  }
  AX[(size_t)gw * F0 + lane] = ((a0 + a2) + (a1 + a3)) * dinv[gw];
}

// ---- GEMM1: H1r = relu(AX @ W1 + b1)  [N,64]@[64,128] ----
__global__ __launch_bounds__(256) void k_gemm1(const float* __restrict__ AX,
    const float* __restrict__ W1, const float* __restrict__ b1,
    float* __restrict__ H1r) {
  __shared__ float Ws[F0][F1];   // 32 KB
  __shared__ float Xs[32][F0];   // 8 KB
  const int tid = threadIdx.x;
  const int row0 = blockIdx.x * 32;
  for (int i = tid; i < F0 * F1 / 4; i += 256)
    reinterpret_cast<float4*>(&Ws[0][0])[i] = reinterpret_cast<const float4*>(W1)[i];
  for (int i = tid; i < 32 * (F0 / 4); i += 256) {
    int r = i / (F0 / 4);
    int n = row0 + r;
    float4 v = make_float4(0.f, 0.f, 0.f, 0.f);
    if (n < N)
      v = reinterpret_cast<const float4*>(AX)[n * (F0 / 4) + (i - r * (F0 / 4))];
    reinterpret_cast<float4*>(&Xs[0][0])[i] = v;
  }
  __syncthreads();
  const int col = tid & (F1 - 1);
  const int rg  = tid >> 7;                      // 0..1
  float acc[16];
  #pragma unroll
  for (int r = 0; r < 16; ++r) acc[r] = 0.f;
  for (int k = 0; k < F0; ++k) {
    float w = Ws[k][col];
    #pragma unroll
    for (int r = 0; r < 16; ++r) acc[r] += Xs[rg + 2 * r][k] * w;
  }
  const float bb = b1[col];
  #pragma unroll
  for (int r = 0; r < 16; ++r) {
    int n = row0 + rg + 2 * r;
    if (n < N) H1r[n * F1 + col] = fmaxf(acc[r] + bb, 0.f);
  }
}

// ---- GEMM2: H2s = (H1r @ W2) * dinv[n]   (src-side prescale for layer-2 agg) ----
__global__ __launch_bounds__(256) void k_gemm2(const float* __restrict__ H1r,
    const float* __restrict__ dinv, const float* __restrict__ W2,
    float* __restrict__ H2s) {
  __shared__ float Ws[F1][F2];   // 16 KB
  __shared__ float Xs[32][F1];   // 16 KB
  const int tid = threadIdx.x;
  const int row0 = blockIdx.x * 32;
  for (int i = tid; i < F1 * F2 / 4; i += 256)
    reinterpret_cast<float4*>(&Ws[0][0])[i] = reinterpret_cast<const float4*>(W2)[i];
  for (int i = tid; i < 32 * (F1 / 4); i += 256) {
    int r = i / (F1 / 4);
    int n = row0 + r;
    float4 v = make_float4(0.f, 0.f, 0.f, 0.f);
    if (n < N)
      v = reinterpret_cast<const float4*>(H1r)[n * (F1 / 4) + (i - r * (F1 / 4))];
    reinterpret_cast<float4*>(&Xs[0][0])[i] = v;
  }
  __syncthreads();
  const int col = tid & (F2 - 1);
  const int rg  = tid >> 5;                      // 0..7
  float acc[4] = {0.f, 0.f, 0.f, 0.f};
  for (int k = 0; k < F1; ++k) {
    float w = Ws[k][col];
    #pragma unroll
    for (int r = 0; r < 4; ++r) acc[r] += Xs[rg + 8 * r][k] * w;
  }
  #pragma unroll
  for (int r = 0; r < 4; ++r) {
    int n = row0 + rg + 8 * r;
    if (n < N) H2s[n * F2 + col] = acc[r] * dinv[n];
  }
}

// ---- layer-2 aggregation + bias: h2[n] = dinv[n]*(H2s[n] + sum_s H2s[s]) + b2 ----
__global__ __launch_bounds__(256) void k_agg2(const int* __restrict__ rowend,
    const int* __restrict__ cnt, const int* __restrict__ ssrc,
    const float* __restrict__ H2s, const float* __restrict__ dinv,
    const float* __restrict__ b2, float* __restrict__ h2) {
  int gw = (blockIdx.x * 256 + threadIdx.x) >> 6;   // node (one wave each)
  int lane = threadIdx.x & 63;
  int f = lane & 31, half = lane >> 5;
  if (gw >= N) return;
  int end   = __builtin_amdgcn_readfirstlane(rowend[gw]);
  int deg   = __builtin_amdgcn_readfirstlane(cnt[gw]);
  int start = end - deg;
  float a0 = (half == 0) ? H2s[(size_t)gw * F2 + f] : 0.f;  // self loop
  float a1 = 0.f, a2 = 0.f, a3 = 0.f;
  for (int e0 = start; e0 < end; e0 += 8) {
    #pragma unroll
    for (int u = 0; u < 4; ++u) {
      int ja = e0 + 2 * u, jb = ja + 1;
      int sa = ssrc[(ja < end) ? ja : start];       // uniform -> s_load
      int sb = ssrc[(jb < end) ? jb : start];
      int s  = half ? sb : sa;
      int j  = half ? jb : ja;
      float v = H2s[(size_t)s * F2 + f];
      v = (j < end) ? v : 0.f;
      if (u == 0) a0 += v;
      else if (u == 1) a1 += v;
      else if (u == 2) a2 += v;
      else a3 += v;
    }
  }
  float acc = (a0 + a2) + (a1 + a3);
  acc += __shfl_xor(acc, 32);
  if (half == 0) h2[(size_t)gw * F2 + f] = dinv[gw] * acc + b2[f];
}

// ---- head: out = h2 @ Wc + bc ----
__global__ __launch_bounds__(256) void k_head(const float* __restrict__ h2,
    const float* __restrict__ Wc, const float* __restrict__ bc,
    float* __restrict__ out) {
  __shared__ float Wcs[F2][F2];  // 4 KB
  __shared__ float Hs[8][F2];
  const int tid = threadIdx.x;
  for (int i = tid; i < F2 * F2; i += 256) Wcs[i >> 5][i & 31] = Wc[i];
  const int r = tid >> 5, j = tid & 31;
  const int n = blockIdx.x * 8 + r;
  float h = (n < N) ? h2[n * F2 + j] : 0.f;
  Hs[r][j] = h;
  __syncthreads();
  if (n < N) {
    float acc = bc[j];
    #pragma unroll
    for (int k = 0; k < F2; ++k) acc += Hs[r][k] * Wcs[k][j];
    out[n * F2 + j] = acc;
  }
}

extern "C" void kernel_launch(void* const* d_in, const int* in_sizes, int n_in,
                              void* d_out, int out_size, void* d_ws, size_t ws_size,
                              hipStream_t stream) {
  const float* x  = (const float*)d_in[0];
  const int*   ei = (const int*)d_in[1];
  const int*   src = ei;                 // edge_index[0]
  const int*   dst = ei + E;             // edge_index[1]
  const float* W1 = (const float*)d_in[2];
  const float* b1 = (const float*)d_in[3];
  const float* W2 = (const float*)d_in[4];
  const float* b2 = (const float*)d_in[5];
  const float* Wc = (const float*)d_in[6];
  const float* bc = (const float*)d_in[7];

  float* out = (float*)d_out;                    // [N, 32] logits
  float* h2  = out + (size_t)N * F2;             // [N, 32] hidden output

  // workspace layout (~42 MB); aliases are time-disjoint:
  //   ebuf (E u32) lives in the AX region  (dead before k_agg1 writes AX)
  //   hist (NBUK*NCHUNK) lives in the big region (dead before k_prescale writes xs)
  int*   cnt        = (int*)d_ws;                // N
  int*   rowend     = cnt + N;                   // N
  int*   bucketBase = rowend + N;                // 256 (uses NBUK+1)
  float* dinv       = (float*)(bucketBase + 256);// N
  int*   ssrc       = (int*)(dinv + N);          // E
  float* AX         = (float*)(ssrc + E);        // N*64
  float* big        = AX + (size_t)N * F0;       // N*128 region
  unsigned int* ebuf = (unsigned int*)AX;        // E u32
  int*   hist       = (int*)big;                 // NBUK*NCHUNK ints
  float* xs         = big;                       // N*64, dead after k_agg1
  float* H1r        = big;                       // N*128, written after xs dead
  float* H2s        = AX;                        // N*32, aliases AX (dead after gemm1)

  k_hist    <<<NCHUNK, 256, 0, stream>>>(dst, hist);
  k_scanbk  <<<NBUK,   256, 0, stream>>>(hist, bucketBase);
  k_scanbase<<<1,      256, 0, stream>>>(bucketBase);
  k_bucket  <<<NCHUNK, 256, 0, stream>>>(src, dst, hist, bucketBase, ebuf);
  k_csr     <<<NBUK,   256, 0, stream>>>(ebuf, bucketBase, cnt, rowend, dinv, ssrc);

  k_prescale<<<(N * (F0 / 4) + 255) / 256, 256, 0, stream>>>(x, dinv, xs);
  k_agg1 <<<(N + 3) / 4, 256, 0, stream>>>(rowend, cnt, ssrc, xs, dinv, AX);
  k_gemm1<<<(N + 31) / 32, 256, 0, stream>>>(AX, W1, b1, H1r);
  k_gemm2<<<(N + 31) / 32, 256, 0, stream>>>(H1r, dinv, W2, H2s);
  k_agg2 <<<(N + 3) / 4, 256, 0, stream>>>(rowend, cnt, ssrc, H2s, dinv, b2, h2);
  k_head <<<(N + 7) / 8, 256, 0, stream>>>(h2, Wc, bc, out);
}

// Round 5
// 150.054 us; speedup vs baseline: 2.5165x; 1.0525x over previous
//
#include <hip/hip_runtime.h>

// GCN forward: two GCNConv layers + linear head.
// Round 5: fusion round. 7 dispatches:
//   k_hist -> k_scanbk -> k_bucket -> k_csr(+dinv+prescale) ->
//   k_agg1 -> k_gemm12 (gemm1+relu+gemm2 fused) -> k_agg2h (agg2+bias+head fused)
// out = dinv[d] * sum_{s in N(d)+self} (dinv[s]*h[s]) per layer.
// Layer1 aggregates BEFORE GEMM (64 feats), layer2 AFTER its GEMM (32 feats).

static constexpr int N  = 50000;
static constexpr int E  = 800000;
static constexpr int F0 = 64;    // input feats
static constexpr int F1 = 128;   // hidden
static constexpr int F2 = 32;    // classes

static constexpr int NBUK   = 196;   // ceil(N/256) buckets of 256 nodes (dst>>8)
static constexpr int CHUNK  = 4096;  // edges per histogram chunk
static constexpr int NCHUNK = 196;   // ceil(E/CHUNK)

// ---- B1: per-chunk LDS histogram over dst buckets ----
__global__ __launch_bounds__(256) void k_hist(const int* __restrict__ dst,
                                              int* __restrict__ hist) {
  __shared__ int hl[NBUK];
  int tid = threadIdx.x, c = blockIdx.x;
  for (int t = tid; t < NBUK; t += 256) hl[t] = 0;
  __syncthreads();
  int e0 = c * CHUNK, m = min(CHUNK, E - e0);
  for (int i = tid; i < m; i += 256)
    atomicAdd(&hl[dst[e0 + i] >> 8], 1);
  __syncthreads();
  for (int t = tid; t < NBUK; t += 256) hist[t * NCHUNK + c] = hl[t];
}

// ---- S1: per-bucket exclusive scan over chunks (in place); bucket totals out ----
__global__ __launch_bounds__(256) void k_scanbk(int* __restrict__ hist,
                                                int* __restrict__ bucketTot) {
  __shared__ int s[256];
  int t = threadIdx.x, b = blockIdx.x;
  int v = (t < NCHUNK) ? hist[b * NCHUNK + t] : 0;
  s[t] = v; __syncthreads();
  for (int off = 1; off < 256; off <<= 1) {
    int u = (t >= off) ? s[t - off] : 0;
    __syncthreads(); s[t] += u; __syncthreads();
  }
  if (t < NCHUNK) hist[b * NCHUNK + t] = s[t] - v;
  if (t == 255) bucketTot[b] = s[255];
}

// ---- B2: scatter edges into bucket-grouped order (packed (dlocal<<16)|src) ----
__global__ __launch_bounds__(256) void k_bucket(const int* __restrict__ src,
    const int* __restrict__ dst, const int* __restrict__ hist,
    const int* __restrict__ bucketTot, unsigned int* __restrict__ ebuf) {
  __shared__ int tl[256], sl[256], startL[NBUK];
  int tid = threadIdx.x, c = blockIdx.x;
  int v = (tid < NBUK) ? bucketTot[tid] : 0;
  tl[tid] = v; sl[tid] = v; __syncthreads();
  for (int off = 1; off < 256; off <<= 1) {
    int u = (tid >= off) ? sl[tid - off] : 0;
    __syncthreads(); sl[tid] += u; __syncthreads();
  }
  for (int t = tid; t < NBUK; t += 256)
    startL[t] = (sl[t] - tl[t]) + hist[t * NCHUNK + c];
  __syncthreads();
  int e0 = c * CHUNK, m = min(CHUNK, E - e0);
  for (int i = tid; i < m; i += 256) {
    int e = e0 + i;
    int d = dst[e], s = src[e];
    int pos = atomicAdd(&startL[d >> 8], 1);           // LDS atomic
    ebuf[pos] = (unsigned int)s | ((unsigned int)(d & 255) << 16);
  }
}

// ---- B3: per-bucket CSR finalize (cnt/rowend/dinv + in-bucket sort) + xs prescale ----
__global__ __launch_bounds__(256) void k_csr(const unsigned int* __restrict__ ebuf,
    const int* __restrict__ bucketTot, const float* __restrict__ x,
    int* __restrict__ cnt, int* __restrict__ rowend, float* __restrict__ dinv,
    int* __restrict__ ssrc, float* __restrict__ xs) {
  __shared__ int tl[256], sl[256], cl[256], sc[256], cur[256];
  __shared__ float dl[256];
  int t = threadIdx.x, b = blockIdx.x;
  // scan bucket totals to get this bucket's base
  int v0 = (t < NBUK) ? bucketTot[t] : 0;
  tl[t] = v0; sl[t] = v0; __syncthreads();
  for (int off = 1; off < 256; off <<= 1) {
    int u = (t >= off) ? sl[t - off] : 0;
    __syncthreads(); sl[t] += u; __syncthreads();
  }
  int base = sl[b] - tl[b];
  int m    = tl[b];
  int node0 = b << 8;
  cl[t] = 0;
  __syncthreads();
  for (int i = t; i < m; i += 256)
    atomicAdd(&cl[(ebuf[base + i] >> 16) & 255], 1);
  __syncthreads();
  int v = cl[t];
  sc[t] = v; __syncthreads();
  for (int off = 1; off < 256; off <<= 1) {
    int u = (t >= off) ? sc[t - off] : 0;
    __syncthreads(); sc[t] += u; __syncthreads();
  }
  int excl = sc[t] - v;
  cur[t] = excl;
  float dv = rsqrtf((float)(v + 1));                  // +1 self-loop
  dl[t] = dv;
  int g = node0 + t;
  if (g < N) {
    cnt[g]    = v;
    rowend[g] = base + excl + v;
    dinv[g]   = dv;
  }
  __syncthreads();
  for (int i = t; i < m; i += 256) {
    unsigned int p = ebuf[base + i];
    int d = (p >> 16) & 255;
    int r = atomicAdd(&cur[d], 1);                     // LDS atomic
    ssrc[base + r] = (int)(p & 0xFFFFu);
  }
  // fused prescale: xs[n] = x[n] * dinv[n] for this bucket's 256 nodes
  for (int i = t; i < 256 * (F0 / 4); i += 256) {
    int nl = i >> 4;                                   // local node
    int n = node0 + nl;
    if (n < N) {
      float4 w = reinterpret_cast<const float4*>(x)[n * (F0 / 4) + (i & 15)];
      float d = dl[nl];
      w.x *= d; w.y *= d; w.z *= d; w.w *= d;
      reinterpret_cast<float4*>(xs)[n * (F0 / 4) + (i & 15)] = w;
    }
  }
}

// ---- layer-1 aggregation: AX[n] = dinv[n] * (xs[n] + sum_s xs[s]) ----
__global__ __launch_bounds__(256) void k_agg1(const int* __restrict__ rowend,
    const int* __restrict__ cnt, const int* __restrict__ ssrc,
    const float* __restrict__ xs, const float* __restrict__ dinv,
    float* __restrict__ AX) {
  int gw = (blockIdx.x * 256 + threadIdx.x) >> 6;   // node (one wave each)
  int lane = threadIdx.x & 63;                      // feature
  if (gw >= N) return;
  int end   = __builtin_amdgcn_readfirstlane(rowend[gw]);
  int deg   = __builtin_amdgcn_readfirstlane(cnt[gw]);
  int start = end - deg;
  float a0 = xs[(size_t)gw * F0 + lane];            // self loop (already *dinv)
  float a1 = 0.f, a2 = 0.f, a3 = 0.f;
  for (int e0 = start; e0 < end; e0 += 8) {
    #pragma unroll
    for (int u = 0; u < 8; ++u) {
      int j  = e0 + u;
      int jc = (j < end) ? j : start;               // uniform clamp
      int s  = ssrc[jc];                            // wave-uniform -> s_load
      float v = xs[(size_t)s * F0 + lane];
      v = (j < end) ? v : 0.f;                      // uniform mask
      if ((u & 3) == 0) a0 += v;
      else if ((u & 3) == 1) a1 += v;
      else if ((u & 3) == 2) a2 += v;
      else a3 += v;
    }
  }
  AX[(size_t)gw * F0 + lane] = ((a0 + a2) + (a1 + a3)) * dinv[gw];
}

// ---- fused GEMM1+relu+GEMM2: H2s = relu(AX@W1+b1)@W2 * dinv ----
__global__ __launch_bounds__(256) void k_gemm12(const float* __restrict__ AX,
    const float* __restrict__ W1, const float* __restrict__ b1,
    const float* __restrict__ W2, const float* __restrict__ dinv,
    float* __restrict__ H2s) {
  __shared__ float Ws1[F0][F1];   // 32 KB
  __shared__ float Ws2[F1][F2];   // 16 KB
  __shared__ float Xs[32][F0];    // 8 KB
  __shared__ float H1s[32][F1];   // 16 KB
  const int tid = threadIdx.x;
  const int row0 = blockIdx.x * 32;
  for (int i = tid; i < F0 * F1 / 4; i += 256)
    reinterpret_cast<float4*>(&Ws1[0][0])[i] = reinterpret_cast<const float4*>(W1)[i];
  for (int i = tid; i < F1 * F2 / 4; i += 256)
    reinterpret_cast<float4*>(&Ws2[0][0])[i] = reinterpret_cast<const float4*>(W2)[i];
  for (int i = tid; i < 32 * (F0 / 4); i += 256) {
    int r = i / (F0 / 4);
    int n = row0 + r;
    float4 v = make_float4(0.f, 0.f, 0.f, 0.f);
    if (n < N)
      v = reinterpret_cast<const float4*>(AX)[n * (F0 / 4) + (i - r * (F0 / 4))];
    reinterpret_cast<float4*>(&Xs[0][0])[i] = v;
  }
  __syncthreads();
  // phase A: H1 tile
  {
    const int col = tid & (F1 - 1);
    const int rg  = tid >> 7;                      // 0..1
    float acc[16];
    #pragma unroll
    for (int r = 0; r < 16; ++r) acc[r] = 0.f;
    for (int k = 0; k < F0; ++k) {
      float w = Ws1[k][col];
      #pragma unroll
      for (int r = 0; r < 16; ++r) acc[r] += Xs[rg + 2 * r][k] * w;
    }
    const float bb = b1[col];
    #pragma unroll
    for (int r = 0; r < 16; ++r)
      H1s[rg + 2 * r][col] = fmaxf(acc[r] + bb, 0.f);
  }
  __syncthreads();
  // phase B: H2 tile
  {
    const int col = tid & (F2 - 1);
    const int rg  = tid >> 5;                      // 0..7
    float acc[4] = {0.f, 0.f, 0.f, 0.f};
    for (int k = 0; k < F1; ++k) {
      float w = Ws2[k][col];
      #pragma unroll
      for (int r = 0; r < 4; ++r) acc[r] += H1s[rg + 8 * r][k] * w;
    }
    #pragma unroll
    for (int r = 0; r < 4; ++r) {
      int n = row0 + rg + 8 * r;
      if (n < N) H2s[n * F2 + col] = acc[r] * dinv[n];
    }
  }
}

// ---- fused layer-2 aggregation + bias + head ----
// h2[n] = dinv[n]*(H2s[n] + sum_s H2s[s]) + b2 ; out[n] = h2[n] @ Wc + bc
__global__ __launch_bounds__(256) void k_agg2h(const int* __restrict__ rowend,
    const int* __restrict__ cnt, const int* __restrict__ ssrc,
    const float* __restrict__ H2s, const float* __restrict__ dinv,
    const float* __restrict__ b2, const float* __restrict__ Wc,
    const float* __restrict__ bc, float* __restrict__ h2,
    float* __restrict__ out) {
  __shared__ float Wcs[F2][F2];  // 4 KB
  const int tid = threadIdx.x;
  for (int i = tid; i < F2 * F2; i += 256) Wcs[i >> 5][i & 31] = Wc[i];
  __syncthreads();
  int gw = (blockIdx.x * 256 + tid) >> 6;           // node (one wave each)
  int lane = tid & 63;
  int f = lane & 31, half = lane >> 5;
  if (gw >= N) return;
  int end   = __builtin_amdgcn_readfirstlane(rowend[gw]);
  int deg   = __builtin_amdgcn_readfirstlane(cnt[gw]);
  int start = end - deg;
  float a0 = (half == 0) ? H2s[(size_t)gw * F2 + f] : 0.f;  // self loop
  float a1 = 0.f, a2 = 0.f, a3 = 0.f;
  for (int e0 = start; e0 < end; e0 += 8) {
    #pragma unroll
    for (int u = 0; u < 4; ++u) {
      int ja = e0 + 2 * u, jb = ja + 1;
      int sa = ssrc[(ja < end) ? ja : start];       // uniform -> s_load
      int sb = ssrc[(jb < end) ? jb : start];
      int s  = half ? sb : sa;
      int j  = half ? jb : ja;
      float v = H2s[(size_t)s * F2 + f];
      v = (j < end) ? v : 0.f;
      if (u == 0) a0 += v;
      else if (u == 1) a1 += v;
      else if (u == 2) a2 += v;
      else a3 += v;
    }
  }
  float acc = (a0 + a2) + (a1 + a3);
  acc += __shfl_xor(acc, 32);
  float h2v = dinv[gw] * acc + b2[f];               // valid in all 64 lanes
  if (half == 0) h2[(size_t)gw * F2 + f] = h2v;
  // head: out[gw][f] = bc[f] + sum_k h2v(k) * Wc[k][f]; halves split k range
  float accо = 0.f;
  #pragma unroll
  for (int kk = 0; kk < 16; ++kk) {
    int k = kk + 16 * half;
    float hk = __shfl(h2v, k);                      // lane k holds feature k
    accо += hk * Wcs[k][f];
  }
  accо += __shfl_xor(accо, 32);
  if (half == 0) out[(size_t)gw * F2 + f] = accо + bc[f];
}

extern "C" void kernel_launch(void* const* d_in, const int* in_sizes, int n_in,
                              void* d_out, int out_size, void* d_ws, size_t ws_size,
                              hipStream_t stream) {
  const float* x  = (const float*)d_in[0];
  const int*   ei = (const int*)d_in[1];
  const int*   src = ei;                 // edge_index[0]
  const int*   dst = ei + E;             // edge_index[1]
  const float* W1 = (const float*)d_in[2];
  const float* b1 = (const float*)d_in[3];
  const float* W2 = (const float*)d_in[4];
  const float* b2 = (const float*)d_in[5];
  const float* Wc = (const float*)d_in[6];
  const float* bc = (const float*)d_in[7];

  float* out = (float*)d_out;                    // [N, 32] logits
  float* h2  = out + (size_t)N * F2;             // [N, 32] hidden output

  // workspace layout (~40 MB of 256 MB) — all disjoint, no aliasing
  int*   cnt        = (int*)d_ws;                // N
  int*   rowend     = cnt + N;                   // N
  int*   bucketTot  = rowend + N;                // 256
  float* dinv       = (float*)(bucketTot + 256); // N
  int*   ssrc       = (int*)(dinv + N);          // E
  unsigned int* ebuf = (unsigned int*)(ssrc + E);// E
  int*   hist       = (int*)(ebuf + E);          // NBUK*NCHUNK
  float* xs         = (float*)(hist + NBUK * NCHUNK + 64); // N*64
  float* AX         = xs + (size_t)N * F0;       // N*64
  float* H2s        = AX + (size_t)N * F0;       // N*32

  k_hist   <<<NCHUNK, 256, 0, stream>>>(dst, hist);
  k_scanbk <<<NBUK,   256, 0, stream>>>(hist, bucketTot);
  k_bucket <<<NCHUNK, 256, 0, stream>>>(src, dst, hist, bucketTot, ebuf);
  k_csr    <<<NBUK,   256, 0, stream>>>(ebuf, bucketTot, x, cnt, rowend, dinv, ssrc, xs);

  k_agg1  <<<(N + 3) / 4, 256, 0, stream>>>(rowend, cnt, ssrc, xs, dinv, AX);
  k_gemm12<<<(N + 31) / 32, 256, 0, stream>>>(AX, W1, b1, W2, dinv, H2s);
  k_agg2h <<<(N + 3) / 4, 256, 0, stream>>>(rowend, cnt, ssrc, H2s, dinv, b2, Wc, bc, h2, out);
}

// Round 6
// 135.586 us; speedup vs baseline: 2.7850x; 1.1067x over previous
//
#include <hip/hip_runtime.h>

// GCN forward: two GCNConv layers + linear head.
// Round 6: un-fused, register-tiled GEMMs (fix FMA:LDS ratio; round-5 fusion
// was LDS-issue-bound at 1 LDS read per FMA). 8 dispatches:
//   k_hist -> k_scanbk -> k_bucket -> k_csr(+dinv+prescale) ->
//   k_agg1 -> k_gemm1 -> k_gemm2 -> k_agg2h (agg2+bias+head fused)
// out = dinv[d] * sum_{s in N(d)+self} (dinv[s]*h[s]) per layer.
// Layer1 aggregates BEFORE GEMM (64 feats), layer2 AFTER its GEMM (32 feats).

static constexpr int N  = 50000;
static constexpr int E  = 800000;
static constexpr int F0 = 64;    // input feats
static constexpr int F1 = 128;   // hidden
static constexpr int F2 = 32;    // classes

static constexpr int NBUK   = 196;   // ceil(N/256) buckets of 256 nodes (dst>>8)
static constexpr int CHUNK  = 4096;  // edges per histogram chunk
static constexpr int NCHUNK = 196;   // ceil(E/CHUNK)

// ---- B1: per-chunk LDS histogram over dst buckets ----
__global__ __launch_bounds__(256) void k_hist(const int* __restrict__ dst,
                                              int* __restrict__ hist) {
  __shared__ int hl[NBUK];
  int tid = threadIdx.x, c = blockIdx.x;
  for (int t = tid; t < NBUK; t += 256) hl[t] = 0;
  __syncthreads();
  int e0 = c * CHUNK, m = min(CHUNK, E - e0);
  for (int i = tid; i < m; i += 256)
    atomicAdd(&hl[dst[e0 + i] >> 8], 1);
  __syncthreads();
  for (int t = tid; t < NBUK; t += 256) hist[t * NCHUNK + c] = hl[t];
}

// ---- S1: per-bucket exclusive scan over chunks (in place); bucket totals out ----
__global__ __launch_bounds__(256) void k_scanbk(int* __restrict__ hist,
                                                int* __restrict__ bucketTot) {
  __shared__ int s[256];
  int t = threadIdx.x, b = blockIdx.x;
  int v = (t < NCHUNK) ? hist[b * NCHUNK + t] : 0;
  s[t] = v; __syncthreads();
  for (int off = 1; off < 256; off <<= 1) {
    int u = (t >= off) ? s[t - off] : 0;
    __syncthreads(); s[t] += u; __syncthreads();
  }
  if (t < NCHUNK) hist[b * NCHUNK + t] = s[t] - v;
  if (t == 255) bucketTot[b] = s[255];
}

// ---- B2: scatter edges into bucket-grouped order (packed (dlocal<<16)|src) ----
__global__ __launch_bounds__(256) void k_bucket(const int* __restrict__ src,
    const int* __restrict__ dst, const int* __restrict__ hist,
    const int* __restrict__ bucketTot, unsigned int* __restrict__ ebuf) {
  __shared__ int tl[256], sl[256], startL[NBUK];
  int tid = threadIdx.x, c = blockIdx.x;
  int v = (tid < NBUK) ? bucketTot[tid] : 0;
  tl[tid] = v; sl[tid] = v; __syncthreads();
  for (int off = 1; off < 256; off <<= 1) {
    int u = (tid >= off) ? sl[tid - off] : 0;
    __syncthreads(); sl[tid] += u; __syncthreads();
  }
  for (int t = tid; t < NBUK; t += 256)
    startL[t] = (sl[t] - tl[t]) + hist[t * NCHUNK + c];
  __syncthreads();
  int e0 = c * CHUNK, m = min(CHUNK, E - e0);
  for (int i = tid; i < m; i += 256) {
    int e = e0 + i;
    int d = dst[e], s = src[e];
    int pos = atomicAdd(&startL[d >> 8], 1);           // LDS atomic
    ebuf[pos] = (unsigned int)s | ((unsigned int)(d & 255) << 16);
  }
}

// ---- B3: per-bucket CSR finalize (cnt/rowend/dinv + in-bucket sort) + xs prescale ----
__global__ __launch_bounds__(256) void k_csr(const unsigned int* __restrict__ ebuf,
    const int* __restrict__ bucketTot, const float* __restrict__ x,
    int* __restrict__ cnt, int* __restrict__ rowend, float* __restrict__ dinv,
    int* __restrict__ ssrc, float* __restrict__ xs) {
  __shared__ int tl[256], sl[256], cl[256], sc[256], cur[256];
  __shared__ float dl[256];
  int t = threadIdx.x, b = blockIdx.x;
  // scan bucket totals to get this bucket's base
  int v0 = (t < NBUK) ? bucketTot[t] : 0;
  tl[t] = v0; sl[t] = v0; __syncthreads();
  for (int off = 1; off < 256; off <<= 1) {
    int u = (t >= off) ? sl[t - off] : 0;
    __syncthreads(); sl[t] += u; __syncthreads();
  }
  int base = sl[b] - tl[b];
  int m    = tl[b];
  int node0 = b << 8;
  cl[t] = 0;
  __syncthreads();
  for (int i = t; i < m; i += 256)
    atomicAdd(&cl[(ebuf[base + i] >> 16) & 255], 1);
  __syncthreads();
  int v = cl[t];
  sc[t] = v; __syncthreads();
  for (int off = 1; off < 256; off <<= 1) {
    int u = (t >= off) ? sc[t - off] : 0;
    __syncthreads(); sc[t] += u; __syncthreads();
  }
  int excl = sc[t] - v;
  cur[t] = excl;
  float dv = rsqrtf((float)(v + 1));                  // +1 self-loop
  dl[t] = dv;
  int g = node0 + t;
  if (g < N) {
    cnt[g]    = v;
    rowend[g] = base + excl + v;
    dinv[g]   = dv;
  }
  __syncthreads();
  for (int i = t; i < m; i += 256) {
    unsigned int p = ebuf[base + i];
    int d = (p >> 16) & 255;
    int r = atomicAdd(&cur[d], 1);                     // LDS atomic
    ssrc[base + r] = (int)(p & 0xFFFFu);
  }
  // fused prescale: xs[n] = x[n] * dinv[n] for this bucket's 256 nodes
  for (int i = t; i < 256 * (F0 / 4); i += 256) {
    int nl = i >> 4;                                   // local node
    int n = node0 + nl;
    if (n < N) {
      float4 w = reinterpret_cast<const float4*>(x)[n * (F0 / 4) + (i & 15)];
      float d = dl[nl];
      w.x *= d; w.y *= d; w.z *= d; w.w *= d;
      reinterpret_cast<float4*>(xs)[n * (F0 / 4) + (i & 15)] = w;
    }
  }
}

// ---- layer-1 aggregation: AX[n] = dinv[n] * (xs[n] + sum_s xs[s]) ----
__global__ __launch_bounds__(256) void k_agg1(const int* __restrict__ rowend,
    const int* __restrict__ cnt, const int* __restrict__ ssrc,
    const float* __restrict__ xs, const float* __restrict__ dinv,
    float* __restrict__ AX) {
  int gw = (blockIdx.x * 256 + threadIdx.x) >> 6;   // node (one wave each)
  int lane = threadIdx.x & 63;                      // feature
  if (gw >= N) return;
  int end   = __builtin_amdgcn_readfirstlane(rowend[gw]);
  int deg   = __builtin_amdgcn_readfirstlane(cnt[gw]);
  int start = end - deg;
  float a0 = xs[(size_t)gw * F0 + lane];            // self loop (already *dinv)
  float a1 = 0.f, a2 = 0.f, a3 = 0.f;
  for (int e0 = start; e0 < end; e0 += 8) {
    #pragma unroll
    for (int u = 0; u < 8; ++u) {
      int j  = e0 + u;
      int jc = (j < end) ? j : start;               // uniform clamp
      int s  = ssrc[jc];                            // wave-uniform -> s_load
      float v = xs[(size_t)s * F0 + lane];
      v = (j < end) ? v : 0.f;                      // uniform mask
      if ((u & 3) == 0) a0 += v;
      else if ((u & 3) == 1) a1 += v;
      else if ((u & 3) == 2) a2 += v;
      else a3 += v;
    }
  }
  AX[(size_t)gw * F0 + lane] = ((a0 + a2) + (a1 + a3)) * dinv[gw];
}

// ---- GEMM1: H1r = relu(AX @ W1 + b1), 64x128 tile, 4r x 8c per thread ----
// W1 in LDS with XOR float4-slot swizzle (slot p = s ^ (s>>2)) so the 16
// column-groups' stride-8-slot reads spread 2-way across bank quads (free).
__global__ __launch_bounds__(256) void k_gemm1(const float* __restrict__ AX,
    const float* __restrict__ W1, const float* __restrict__ b1,
    float* __restrict__ H1r) {
  __shared__ float Ws[F0 * F1];      // 32 KB, [64][32 float4-slots] swizzled
  __shared__ float Xs[64][F0 + 4];   // 17.4 KB, stride 68 -> clean broadcast
  const int tid = threadIdx.x;
  const int row0 = blockIdx.x * 64;
  float4* Wsf4 = reinterpret_cast<float4*>(Ws);
  for (int i = tid; i < F0 * F1 / 4; i += 256) {
    int k = i >> 5, s = i & 31;
    int p = s ^ (s >> 2);
    Wsf4[k * 32 + p] = reinterpret_cast<const float4*>(W1)[i];
  }
  for (int i = tid; i < 64 * 16; i += 256) {
    int r = i >> 4, c4 = i & 15;
    int n = row0 + r;
    float4 v = make_float4(0.f, 0.f, 0.f, 0.f);
    if (n < N) v = reinterpret_cast<const float4*>(AX)[n * 16 + c4];
    *reinterpret_cast<float4*>(&Xs[r][c4 * 4]) = v;
  }
  __syncthreads();
  const int cg = tid & 15, rg = tid >> 4;
  const int c0 = cg * 8;
  const int s0 = 2 * cg, s1 = 2 * cg + 1;
  const int p0 = s0 ^ (s0 >> 2), p1 = s1 ^ (s1 >> 2);
  float acc[4][8];
  #pragma unroll
  for (int i = 0; i < 4; ++i)
    #pragma unroll
    for (int j = 0; j < 8; ++j) acc[i][j] = 0.f;
  for (int k0 = 0; k0 < F0; k0 += 4) {
    float x0[4], x1[4], x2[4], x3[4];
    *reinterpret_cast<float4*>(x0) = *reinterpret_cast<const float4*>(&Xs[rg * 4 + 0][k0]);
    *reinterpret_cast<float4*>(x1) = *reinterpret_cast<const float4*>(&Xs[rg * 4 + 1][k0]);
    *reinterpret_cast<float4*>(x2) = *reinterpret_cast<const float4*>(&Xs[rg * 4 + 2][k0]);
    *reinterpret_cast<float4*>(x3) = *reinterpret_cast<const float4*>(&Xs[rg * 4 + 3][k0]);
    #pragma unroll
    for (int kk = 0; kk < 4; ++kk) {
      float w[8];
      *reinterpret_cast<float4*>(w)     = Wsf4[(k0 + kk) * 32 + p0];
      *reinterpret_cast<float4*>(w + 4) = Wsf4[(k0 + kk) * 32 + p1];
      #pragma unroll
      for (int j = 0; j < 8; ++j) {
        acc[0][j] = fmaf(x0[kk], w[j], acc[0][j]);
        acc[1][j] = fmaf(x1[kk], w[j], acc[1][j]);
        acc[2][j] = fmaf(x2[kk], w[j], acc[2][j]);
        acc[3][j] = fmaf(x3[kk], w[j], acc[3][j]);
      }
    }
  }
  float bb[8];
  *reinterpret_cast<float4*>(bb)     = *reinterpret_cast<const float4*>(&b1[c0]);
  *reinterpret_cast<float4*>(bb + 4) = *reinterpret_cast<const float4*>(&b1[c0 + 4]);
  #pragma unroll
  for (int i = 0; i < 4; ++i) {
    int n = row0 + rg * 4 + i;
    if (n < N) {
      float o[8];
      #pragma unroll
      for (int j = 0; j < 8; ++j) o[j] = fmaxf(acc[i][j] + bb[j], 0.f);
      *reinterpret_cast<float4*>(&H1r[(size_t)n * F1 + c0])     = *reinterpret_cast<float4*>(o);
      *reinterpret_cast<float4*>(&H1r[(size_t)n * F1 + c0 + 4]) = *reinterpret_cast<float4*>(o + 4);
    }
  }
}

// ---- GEMM2: H2s = (H1r @ W2) * dinv, 128-row tile, 2r x 8c per thread ----
// H1 rows read directly from global (4x redundancy, L2/L3-served); only W2 in LDS.
__global__ __launch_bounds__(256) void k_gemm2(const float* __restrict__ H1r,
    const float* __restrict__ dinv, const float* __restrict__ W2,
    float* __restrict__ H2s) {
  __shared__ float Ws[F1 * F2];      // 16 KB
  const int tid = threadIdx.x;
  const int row0 = blockIdx.x * 128;
  float4* Wsf4 = reinterpret_cast<float4*>(Ws);
  for (int i = tid; i < F1 * F2 / 4; i += 256)
    Wsf4[i] = reinterpret_cast<const float4*>(W2)[i];
  __syncthreads();
  const int cg = tid & 3, rg = tid >> 2;           // cols cg*8.. ; rows rg*2..
  const int c0 = cg * 8;
  const int n0 = row0 + rg * 2, n1 = n0 + 1;
  const int na = (n0 < N) ? n0 : 0, nb = (n1 < N) ? n1 : 0;
  const float4* X0 = reinterpret_cast<const float4*>(H1r + (size_t)na * F1);
  const float4* X1 = reinterpret_cast<const float4*>(H1r + (size_t)nb * F1);
  float acc[2][8];
  #pragma unroll
  for (int i = 0; i < 2; ++i)
    #pragma unroll
    for (int j = 0; j < 8; ++j) acc[i][j] = 0.f;
  for (int k0 = 0; k0 < F1; k0 += 4) {
    float x0[4], x1[4];
    *reinterpret_cast<float4*>(x0) = X0[k0 >> 2];
    *reinterpret_cast<float4*>(x1) = X1[k0 >> 2];
    #pragma unroll
    for (int kk = 0; kk < 4; ++kk) {
      float w[8];
      *reinterpret_cast<float4*>(w)     = Wsf4[(k0 + kk) * 8 + cg * 2];
      *reinterpret_cast<float4*>(w + 4) = Wsf4[(k0 + kk) * 8 + cg * 2 + 1];
      #pragma unroll
      for (int j = 0; j < 8; ++j) {
        acc[0][j] = fmaf(x0[kk], w[j], acc[0][j]);
        acc[1][j] = fmaf(x1[kk], w[j], acc[1][j]);
      }
    }
  }
  #pragma unroll
  for (int i = 0; i < 2; ++i) {
    int n = n0 + i;
    if (n < N) {
      float d = dinv[n];
      float o[8];
      #pragma unroll
      for (int j = 0; j < 8; ++j) o[j] = acc[i][j] * d;
      *reinterpret_cast<float4*>(&H2s[(size_t)n * F2 + c0])     = *reinterpret_cast<float4*>(o);
      *reinterpret_cast<float4*>(&H2s[(size_t)n * F2 + c0 + 4]) = *reinterpret_cast<float4*>(o + 4);
    }
  }
}

// ---- fused layer-2 aggregation + bias + head ----
// h2[n] = dinv[n]*(H2s[n] + sum_s H2s[s]) + b2 ; out[n] = h2[n] @ Wc + bc
__global__ __launch_bounds__(256) void k_agg2h(const int* __restrict__ rowend,
    const int* __restrict__ cnt, const int* __restrict__ ssrc,
    const float* __restrict__ H2s, const float* __restrict__ dinv,
    const float* __restrict__ b2, const float* __restrict__ Wc,
    const float* __restrict__ bc, float* __restrict__ h2,
    float* __restrict__ out) {
  __shared__ float Wcs[F2][F2];  // 4 KB
  const int tid = threadIdx.x;
  for (int i = tid; i < F2 * F2; i += 256) Wcs[i >> 5][i & 31] = Wc[i];
  __syncthreads();
  int gw = (blockIdx.x * 256 + tid) >> 6;           // node (one wave each)
  int lane = tid & 63;
  int f = lane & 31, half = lane >> 5;
  if (gw >= N) return;
  int end   = __builtin_amdgcn_readfirstlane(rowend[gw]);
  int deg   = __builtin_amdgcn_readfirstlane(cnt[gw]);
  int start = end - deg;
  float a0 = (half == 0) ? H2s[(size_t)gw * F2 + f] : 0.f;  // self loop
  float a1 = 0.f, a2 = 0.f, a3 = 0.f;
  for (int e0 = start; e0 < end; e0 += 8) {
    #pragma unroll
    for (int u = 0; u < 4; ++u) {
      int ja = e0 + 2 * u, jb = ja + 1;
      int sa = ssrc[(ja < end) ? ja : start];       // uniform -> s_load
      int sb = ssrc[(jb < end) ? jb : start];
      int s  = half ? sb : sa;
      int j  = half ? jb : ja;
      float v = H2s[(size_t)s * F2 + f];
      v = (j < end) ? v : 0.f;
      if (u == 0) a0 += v;
      else if (u == 1) a1 += v;
      else if (u == 2) a2 += v;
      else a3 += v;
    }
  }
  float acc = (a0 + a2) + (a1 + a3);
  acc += __shfl_xor(acc, 32);
  float h2v = dinv[gw] * acc + b2[f];               // valid in all 64 lanes
  if (half == 0) h2[(size_t)gw * F2 + f] = h2v;
  // head: out[gw][f] = bc[f] + sum_k h2v(k) * Wc[k][f]; halves split k range
  float acco = 0.f;
  #pragma unroll
  for (int kk = 0; kk < 16; ++kk) {
    int k = kk + 16 * half;
    float hk = __shfl(h2v, k);                      // lane k holds feature k
    acco += hk * Wcs[k][f];
  }
  acco += __shfl_xor(acco, 32);
  if (half == 0) out[(size_t)gw * F2 + f] = acco + bc[f];
}

extern "C" void kernel_launch(void* const* d_in, const int* in_sizes, int n_in,
                              void* d_out, int out_size, void* d_ws, size_t ws_size,
                              hipStream_t stream) {
  const float* x  = (const float*)d_in[0];
  const int*   ei = (const int*)d_in[1];
  const int*   src = ei;                 // edge_index[0]
  const int*   dst = ei + E;             // edge_index[1]
  const float* W1 = (const float*)d_in[2];
  const float* b1 = (const float*)d_in[3];
  const float* W2 = (const float*)d_in[4];
  const float* b2 = (const float*)d_in[5];
  const float* Wc = (const float*)d_in[6];
  const float* bc = (const float*)d_in[7];

  float* out = (float*)d_out;                    // [N, 32] logits
  float* h2  = out + (size_t)N * F2;             // [N, 32] hidden output

  // workspace layout (~66 MB of 256 MB) — all disjoint, no aliasing
  int*   cnt        = (int*)d_ws;                // N
  int*   rowend     = cnt + N;                   // N
  int*   bucketTot  = rowend + N;                // 256
  float* dinv       = (float*)(bucketTot + 256); // N
  int*   ssrc       = (int*)(dinv + N);          // E
  unsigned int* ebuf = (unsigned int*)(ssrc + E);// E
  int*   hist       = (int*)(ebuf + E);          // NBUK*NCHUNK
  float* xs         = (float*)(hist + NBUK * NCHUNK + 64); // N*64
  float* AX         = xs + (size_t)N * F0;       // N*64
  float* H1r        = AX + (size_t)N * F0;       // N*128
  float* H2s        = H1r + (size_t)N * F1;      // N*32

  k_hist   <<<NCHUNK, 256, 0, stream>>>(dst, hist);
  k_scanbk <<<NBUK,   256, 0, stream>>>(hist, bucketTot);
  k_bucket <<<NCHUNK, 256, 0, stream>>>(src, dst, hist, bucketTot, ebuf);
  k_csr    <<<NBUK,   256, 0, stream>>>(ebuf, bucketTot, x, cnt, rowend, dinv, ssrc, xs);

  k_agg1 <<<(N + 3) / 4, 256, 0, stream>>>(rowend, cnt, ssrc, xs, dinv, AX);
  k_gemm1<<<(N + 63) / 64, 256, 0, stream>>>(AX, W1, b1, H1r);
  k_gemm2<<<(N + 127) / 128, 256, 0, stream>>>(H1r, dinv, W2, H2s);
  k_agg2h<<<(N + 3) / 4, 256, 0, stream>>>(rowend, cnt, ssrc, H2s, dinv, b2, Wc, bc, h2, out);
}